// Round 4
// baseline (806.822 us; speedup 1.0000x reference)
//
#include <hip/hip_runtime.h>
#include <float.h>

#define L_TOK 65536
#define DIM   64
#define NCODE 1024

// ---------------------------------------------------------------------------
// Kernel A: per-code ||e||^2 (fp32), sequential-k chain.
// ---------------------------------------------------------------------------
__global__ __launch_bounds__(256) void esum_kernel(const float* __restrict__ emb,
                                                   float* __restrict__ esum) {
    int n = blockIdx.x * 256 + threadIdx.x;
    if (n >= NCODE) return;
    const float* e = emb + ((size_t)n << 6);
    float s = 0.f;
#pragma unroll
    for (int k = 0; k < DIM; ++k) s = fmaf(e[k], e[k], s);
    esum[n] = s;
}

// ---------------------------------------------------------------------------
// Kernel B: argmin.
//  - block = 512 threads = 8 waves, all covering the same 64 tokens;
//    wave w owns codes [128w, 128w+128). 1024 blocks -> 8192 waves = 100%
//    occupancy (round-3 was grid-limited at 38%).
//  - z tile staged in LDS TRANSPOSED zt[k][tok]: inner read zt[k][lane] is
//    bank = lane%32 -> 2 lanes/bank = conflict-free; per-lane live state is
//    only ~24 VGPRs so the compiler has nothing to spill/reload (round-2/3
//    pathology: VGPR=44 with z re-loaded per iteration).
//  - e rows wave-uniform -> scalarized s_load feeding v_fmac(SGPR,VGPR).
//  - numerics identical to the passing kernels:
//      a  = sequential fmaf chain k=0..63 (8 independent code chains)
//      zs = sequential fmaf chain k=0..63
//      d  = fmaf(a, -2, zs+esum[c])  ==  (zs+esum[c]) - 2*a  bitwise
//      ascending strict '<' scan; lowest-index tie-break across waves.
// ---------------------------------------------------------------------------
__global__ __launch_bounds__(512, 8) void argmin_kernel(const float* __restrict__ z,
                                                        const float* __restrict__ emb,
                                                        const float* __restrict__ esum,
                                                        float* __restrict__ idx_out) {
    __shared__ float zt[DIM][64];   // [k][tok]  16 KB
    __shared__ float sb[8][64];
    __shared__ int   si[8][64];

    const int t    = threadIdx.x;
    const int lane = t & 63;
    const int wid  = __builtin_amdgcn_readfirstlane(t >> 6);

    // Stage z tile (coalesced global read, transposed LDS write; once).
    {
        const int tok = t >> 3;          // 0..63
        const int kk  = (t & 7) * 8;     // 0,8,..,56
        const float* src = z + ((size_t)(blockIdx.x * 64 + tok) << 6) + kk;
        float4 v0 = ((const float4*)src)[0];
        float4 v1 = ((const float4*)src)[1];
        zt[kk + 0][tok] = v0.x; zt[kk + 1][tok] = v0.y;
        zt[kk + 2][tok] = v0.z; zt[kk + 3][tok] = v0.w;
        zt[kk + 4][tok] = v1.x; zt[kk + 5][tok] = v1.y;
        zt[kk + 6][tok] = v1.z; zt[kk + 7][tok] = v1.w;
    }
    __syncthreads();

    // ||z||^2, sequential k (same order as all passing rounds).
    float zs = 0.f;
#pragma unroll
    for (int k = 0; k < DIM; ++k) {
        float zk = zt[k][lane];
        zs = fmaf(zk, zk, zs);
    }

    float best = FLT_MAX;
    int   bi   = 0;
    const int cbase = wid * 128;     // wave-uniform

    for (int c0 = cbase; c0 < cbase + 128; c0 += 8) {
        const float* __restrict__ e0 = emb + ((size_t)(c0 + 0) << 6);
        const float* __restrict__ e1 = emb + ((size_t)(c0 + 1) << 6);
        const float* __restrict__ e2 = emb + ((size_t)(c0 + 2) << 6);
        const float* __restrict__ e3 = emb + ((size_t)(c0 + 3) << 6);
        const float* __restrict__ e4 = emb + ((size_t)(c0 + 4) << 6);
        const float* __restrict__ e5 = emb + ((size_t)(c0 + 5) << 6);
        const float* __restrict__ e6 = emb + ((size_t)(c0 + 6) << 6);
        const float* __restrict__ e7 = emb + ((size_t)(c0 + 7) << 6);
        float a0 = 0.f, a1 = 0.f, a2 = 0.f, a3 = 0.f;
        float a4 = 0.f, a5 = 0.f, a6 = 0.f, a7 = 0.f;
#pragma unroll
        for (int k = 0; k < DIM; ++k) {
            float zk = zt[k][lane];          // 1 ds_read_b32, conflict-free
            a0 = fmaf(zk, e0[k], a0);        // v_fmac(vgpr, sgpr)
            a1 = fmaf(zk, e1[k], a1);
            a2 = fmaf(zk, e2[k], a2);
            a3 = fmaf(zk, e3[k], a3);
            a4 = fmaf(zk, e4[k], a4);
            a5 = fmaf(zk, e5[k], a5);
            a6 = fmaf(zk, e6[k], a6);
            a7 = fmaf(zk, e7[k], a7);
        }
        float d0 = fmaf(a0, -2.0f, zs + esum[c0 + 0]);
        float d1 = fmaf(a1, -2.0f, zs + esum[c0 + 1]);
        float d2 = fmaf(a2, -2.0f, zs + esum[c0 + 2]);
        float d3 = fmaf(a3, -2.0f, zs + esum[c0 + 3]);
        float d4 = fmaf(a4, -2.0f, zs + esum[c0 + 4]);
        float d5 = fmaf(a5, -2.0f, zs + esum[c0 + 5]);
        float d6 = fmaf(a6, -2.0f, zs + esum[c0 + 6]);
        float d7 = fmaf(a7, -2.0f, zs + esum[c0 + 7]);
        if (d0 < best) { best = d0; bi = c0 + 0; }
        if (d1 < best) { best = d1; bi = c0 + 1; }
        if (d2 < best) { best = d2; bi = c0 + 2; }
        if (d3 < best) { best = d3; bi = c0 + 3; }
        if (d4 < best) { best = d4; bi = c0 + 4; }
        if (d5 < best) { best = d5; bi = c0 + 5; }
        if (d6 < best) { best = d6; bi = c0 + 6; }
        if (d7 < best) { best = d7; bi = c0 + 7; }
    }

    sb[wid][lane] = best;
    si[wid][lane] = bi;
    __syncthreads();

    if (t < 64) {
        float b = sb[0][lane];
        int   i = si[0][lane];
#pragma unroll
        for (int w = 1; w < 8; ++w) {
            float ob = sb[w][lane];
            int   oi = si[w][lane];
            if (ob < b || (ob == b && oi < i)) { b = ob; i = oi; }
        }
        idx_out[blockIdx.x * 64 + lane] = (float)i;
    }
}

// ---------------------------------------------------------------------------
// Kernel C: z_q_st + per-block f64 loss partials (unchanged).
// ---------------------------------------------------------------------------
__global__ __launch_bounds__(256) void output_kernel(const float* __restrict__ z,
                                                     const float* __restrict__ emb,
                                                     const float* __restrict__ idx_f,
                                                     float* __restrict__ zq_out,
                                                     double* __restrict__ partials) {
    int gid = blockIdx.x * 256 + threadIdx.x;
    int l = gid >> 6;
    int k = gid & 63;
    int idx = (int)idx_f[l];

    float zv = z[gid];
    float ev = emb[(idx << 6) + k];
    float t    = ev - zv;
    float outv = zv + t;
    zq_out[gid] = outv;

    float sq = t * t;

    __shared__ double red[256];
    red[threadIdx.x] = (double)sq;
    __syncthreads();
    for (int s = 128; s > 0; s >>= 1) {
        if (threadIdx.x < s) red[threadIdx.x] += red[threadIdx.x + s];
        __syncthreads();
    }
    if (threadIdx.x == 0) partials[blockIdx.x] = red[0];
}

// ---------------------------------------------------------------------------
// Kernel D: final deterministic reduction (unchanged).
// ---------------------------------------------------------------------------
__global__ __launch_bounds__(256) void loss_kernel(const double* __restrict__ partials,
                                                   float* __restrict__ loss_out) {
    __shared__ double red[256];
    int t = threadIdx.x;
    double s = 0.0;
    for (int i = 0; i < 64; ++i) s += partials[t * 64 + i];
    red[t] = s;
    __syncthreads();
    for (int st = 128; st > 0; st >>= 1) {
        if (t < st) red[t] += red[t + st];
        __syncthreads();
    }
    if (t == 0) {
        double m  = red[0] / (double)(L_TOK * DIM);
        float  mf = (float)m;
        loss_out[0] = 0.25f * mf + mf;
    }
}

extern "C" void kernel_launch(void* const* d_in, const int* in_sizes, int n_in,
                              void* d_out, int out_size, void* d_ws, size_t ws_size,
                              hipStream_t stream) {
    const float* z   = (const float*)d_in[0];
    const float* emb = (const float*)d_in[1];

    float* out   = (float*)d_out;
    float* zq    = out;                 // [0, 4194304)
    float* loss  = out + 4194304;       // [4194304]
    float* idxf  = out + 4194305;       // [4194305, 4259841)

    float*  esum     = (float*)d_ws;                          // 1024 f32
    double* partials = (double*)((char*)d_ws + 8192);         // 16384 f64

    esum_kernel  <<<4,     256, 0, stream>>>(emb, esum);
    argmin_kernel<<<1024,  512, 0, stream>>>(z, emb, esum, idxf);
    output_kernel<<<16384, 256, 0, stream>>>(z, emb, idxf, zq, partials);
    loss_kernel  <<<1,     256, 0, stream>>>(partials, loss);
}

// Round 5
// 184.648 us; speedup vs baseline: 4.3695x; 4.3695x over previous
//
#include <hip/hip_runtime.h>
#include <float.h>

#define L_TOK 65536
#define DIM   64
#define NCODE 1024

// ---------------------------------------------------------------------------
// Kernel A: per-code ||e||^2 (fp32), sequential-k chain.
// ---------------------------------------------------------------------------
__global__ __launch_bounds__(256) void esum_kernel(const float* __restrict__ emb,
                                                   float* __restrict__ esum) {
    int n = blockIdx.x * 256 + threadIdx.x;
    if (n >= NCODE) return;
    const float* e = emb + ((size_t)n << 6);
    float s = 0.f;
#pragma unroll
    for (int k = 0; k < DIM; ++k) s = fmaf(e[k], e[k], s);
    esum[n] = s;
}

// ---------------------------------------------------------------------------
// Kernel B: argmin — EXACT round-2 body (proven bitwise-correct, 180 us) with
// one change: __launch_bounds__(256, 4) raises the VGPR cap to 128 so the
// 64-float z row actually STAYS in registers.
//   Round-2/3 pathology: default heuristic chose 44 VGPRs -> z re-loaded from
//   L1 every iteration (L1 stream ~110 us co-equal with VALU).
//   Round-4 pathology: LDS z + 64-VGPR cap -> compiler hoisted the LDS reads
//   into a 64-float per-thread array and spilled it to SCRATCH (2.4 GB HBM).
// With 128-VGPR budget: zreg[64] + 4 accumulators + addressing ~ 100 VGPRs,
// hot loop = pure v_fmac(SGPR e-value, VGPR z) + scalar loads. 1024 blocks =
// exactly 4 resident blocks/CU (16 waves/CU).
// Numerics identical: sequential-k fmaf chains, d = (zs+esum[c]) - 2*a,
// ascending strict '<' scan, lowest-index tie-break across waves.
// ---------------------------------------------------------------------------
__global__ __launch_bounds__(256, 4) void argmin_kernel(const float* __restrict__ z,
                                                        const float* __restrict__ emb,
                                                        const float* __restrict__ esum,
                                                        float* __restrict__ idx_out) {
    const int lane  = threadIdx.x & 63;
    const int wid   = __builtin_amdgcn_readfirstlane(threadIdx.x >> 6);
    const int token = blockIdx.x * 64 + lane;

    const float* zr = z + ((size_t)token << 6);
    float zreg[DIM];
#pragma unroll
    for (int i = 0; i < 16; ++i) {
        float4 v = ((const float4*)zr)[i];
        zreg[4*i+0] = v.x; zreg[4*i+1] = v.y;
        zreg[4*i+2] = v.z; zreg[4*i+3] = v.w;
    }

    float zs = 0.f;
#pragma unroll
    for (int k = 0; k < DIM; ++k) zs = fmaf(zreg[k], zreg[k], zs);

    float best = FLT_MAX;
    int   bi   = 0;
    const int cbase = wid * 256;   // wave-uniform

    for (int c0 = cbase; c0 < cbase + 256; c0 += 4) {
        const float* __restrict__ e0 = emb + ((size_t)(c0 + 0) << 6);
        const float* __restrict__ e1 = emb + ((size_t)(c0 + 1) << 6);
        const float* __restrict__ e2 = emb + ((size_t)(c0 + 2) << 6);
        const float* __restrict__ e3 = emb + ((size_t)(c0 + 3) << 6);
        float a0 = 0.f, a1 = 0.f, a2 = 0.f, a3 = 0.f;
#pragma unroll
        for (int k = 0; k < DIM; ++k) {
            float zk = zreg[k];
            a0 = fmaf(zk, e0[k], a0);
            a1 = fmaf(zk, e1[k], a1);
            a2 = fmaf(zk, e2[k], a2);
            a3 = fmaf(zk, e3[k], a3);
        }
        float t0 = zs + esum[c0 + 0];
        float t1 = zs + esum[c0 + 1];
        float t2 = zs + esum[c0 + 2];
        float t3 = zs + esum[c0 + 3];
        float d0 = t0 - 2.0f * a0;
        float d1 = t1 - 2.0f * a1;
        float d2 = t2 - 2.0f * a2;
        float d3 = t3 - 2.0f * a3;
        if (d0 < best) { best = d0; bi = c0 + 0; }
        if (d1 < best) { best = d1; bi = c0 + 1; }
        if (d2 < best) { best = d2; bi = c0 + 2; }
        if (d3 < best) { best = d3; bi = c0 + 3; }
    }

    __shared__ float sb[4][64];
    __shared__ int   si[4][64];
    sb[wid][lane] = best;
    si[wid][lane] = bi;
    __syncthreads();

    if (threadIdx.x < 64) {
        float b = sb[0][lane];
        int   i = si[0][lane];
#pragma unroll
        for (int w = 1; w < 4; ++w) {
            float ob = sb[w][lane];
            int   oi = si[w][lane];
            if (ob < b || (ob == b && oi < i)) { b = ob; i = oi; }
        }
        idx_out[token] = (float)i;
    }
}

// ---------------------------------------------------------------------------
// Kernel C: z_q_st + per-block f64 loss partials (unchanged).
// ---------------------------------------------------------------------------
__global__ __launch_bounds__(256) void output_kernel(const float* __restrict__ z,
                                                     const float* __restrict__ emb,
                                                     const float* __restrict__ idx_f,
                                                     float* __restrict__ zq_out,
                                                     double* __restrict__ partials) {
    int gid = blockIdx.x * 256 + threadIdx.x;
    int l = gid >> 6;
    int k = gid & 63;
    int idx = (int)idx_f[l];

    float zv = z[gid];
    float ev = emb[(idx << 6) + k];
    float t    = ev - zv;
    float outv = zv + t;
    zq_out[gid] = outv;

    float sq = t * t;

    __shared__ double red[256];
    red[threadIdx.x] = (double)sq;
    __syncthreads();
    for (int s = 128; s > 0; s >>= 1) {
        if (threadIdx.x < s) red[threadIdx.x] += red[threadIdx.x + s];
        __syncthreads();
    }
    if (threadIdx.x == 0) partials[blockIdx.x] = red[0];
}

// ---------------------------------------------------------------------------
// Kernel D: final deterministic reduction (unchanged).
// ---------------------------------------------------------------------------
__global__ __launch_bounds__(256) void loss_kernel(const double* __restrict__ partials,
                                                   float* __restrict__ loss_out) {
    __shared__ double red[256];
    int t = threadIdx.x;
    double s = 0.0;
    for (int i = 0; i < 64; ++i) s += partials[t * 64 + i];
    red[t] = s;
    __syncthreads();
    for (int st = 128; st > 0; st >>= 1) {
        if (t < st) red[t] += red[t + st];
        __syncthreads();
    }
    if (t == 0) {
        double m  = red[0] / (double)(L_TOK * DIM);
        float  mf = (float)m;
        loss_out[0] = 0.25f * mf + mf;
    }
}

extern "C" void kernel_launch(void* const* d_in, const int* in_sizes, int n_in,
                              void* d_out, int out_size, void* d_ws, size_t ws_size,
                              hipStream_t stream) {
    const float* z   = (const float*)d_in[0];
    const float* emb = (const float*)d_in[1];

    float* out   = (float*)d_out;
    float* zq    = out;                 // [0, 4194304)
    float* loss  = out + 4194304;       // [4194304]
    float* idxf  = out + 4194305;       // [4194305, 4259841)

    float*  esum     = (float*)d_ws;                          // 1024 f32
    double* partials = (double*)((char*)d_ws + 8192);         // 16384 f64

    esum_kernel  <<<4,     256, 0, stream>>>(emb, esum);
    argmin_kernel<<<1024,  256, 0, stream>>>(z, emb, esum, idxf);
    output_kernel<<<16384, 256, 0, stream>>>(z, emb, idxf, zq, partials);
    loss_kernel  <<<1,     256, 0, stream>>>(partials, loss);
}

// Round 6
// 183.983 us; speedup vs baseline: 4.3853x; 1.0036x over previous
//
#include <hip/hip_runtime.h>
#include <float.h>

#define L_TOK 65536
#define DIM   64
#define NCODE 1024

// ---------------------------------------------------------------------------
// Kernel A: per-code ||e||^2 (fp32), sequential-k chain.
// ---------------------------------------------------------------------------
__global__ __launch_bounds__(256) void esum_kernel(const float* __restrict__ emb,
                                                   float* __restrict__ esum) {
    int n = blockIdx.x * 256 + threadIdx.x;
    if (n >= NCODE) return;
    const float* e = emb + ((size_t)n << 6);
    float s = 0.f;
#pragma unroll
    for (int k = 0; k < DIM; ++k) s = fmaf(e[k], e[k], s);
    esum[n] = s;
}

// ---------------------------------------------------------------------------
// Kernel B: argmin — round-2 body (proven bitwise-correct) + HARD z pin.
//
// History of the z-residency fight (counters as evidence):
//   r2/r5: scheduler SINKS the 16 global_load_dwordx4 into the code loop
//          (VGPR=44, ~110us L1/L2 z-reload stream co-equal with VALU).
//   r3:    empty asm("" : "+v") pin was ELIDED (no instruction emitted, load
//          stays the reaching def) -> identical counters.
//   r4:    LDS copy + 64-VGPR cap -> compiler hoisted to scratch (2.4GB HBM).
// Fix: pass each z value through a REAL instruction (v_max_f32 %0,%0,%0 --
// bitwise identity incl. -0). The def is now an asm inst, not a load:
// single-inst remat cannot rebuild it, sinking is impossible. Allocator must
// keep 64 VGPRs live -- fits the 128-VGPR budget at 4 waves/SIMD
// (launch_bounds(256,4): 4 blocks/CU; register-resident z CANNOT go to 8
// waves/SIMD since that caps VGPR at 64 -- round-4 trap).
//
// Numerics identical: sequential-k fmaf chains, d = (zs+esum[c]) - 2*a,
// ascending strict '<' scan, lowest-index tie-break across waves.
// ---------------------------------------------------------------------------
__global__ __launch_bounds__(256, 4) void argmin_kernel(const float* __restrict__ z,
                                                        const float* __restrict__ emb,
                                                        const float* __restrict__ esum,
                                                        float* __restrict__ idx_out) {
    const int lane  = threadIdx.x & 63;
    const int wid   = __builtin_amdgcn_readfirstlane(threadIdx.x >> 6);
    const int token = blockIdx.x * 64 + lane;

    const float* zr = z + ((size_t)token << 6);
    float zreg[DIM];
#pragma unroll
    for (int i = 0; i < 16; ++i) {
        float4 v = ((const float4*)zr)[i];
        zreg[4*i+0] = v.x; zreg[4*i+1] = v.y;
        zreg[4*i+2] = v.z; zreg[4*i+3] = v.w;
    }
    // HARD pin: real instruction, bitwise identity, non-elidable, non-remat.
#pragma unroll
    for (int i = 0; i < DIM; ++i) {
        asm volatile("v_max_f32 %0, %0, %0" : "+v"(zreg[i]));
    }

    float zs = 0.f;
#pragma unroll
    for (int k = 0; k < DIM; ++k) zs = fmaf(zreg[k], zreg[k], zs);

    float best = FLT_MAX;
    int   bi   = 0;
    const int cbase = wid * 256;   // wave-uniform

    for (int c0 = cbase; c0 < cbase + 256; c0 += 4) {
        const float* __restrict__ e0 = emb + ((size_t)(c0 + 0) << 6);
        const float* __restrict__ e1 = emb + ((size_t)(c0 + 1) << 6);
        const float* __restrict__ e2 = emb + ((size_t)(c0 + 2) << 6);
        const float* __restrict__ e3 = emb + ((size_t)(c0 + 3) << 6);
        float a0 = 0.f, a1 = 0.f, a2 = 0.f, a3 = 0.f;
#pragma unroll
        for (int k = 0; k < DIM; ++k) {
            float zk = zreg[k];
            a0 = fmaf(zk, e0[k], a0);
            a1 = fmaf(zk, e1[k], a1);
            a2 = fmaf(zk, e2[k], a2);
            a3 = fmaf(zk, e3[k], a3);
        }
        float t0 = zs + esum[c0 + 0];
        float t1 = zs + esum[c0 + 1];
        float t2 = zs + esum[c0 + 2];
        float t3 = zs + esum[c0 + 3];
        float d0 = t0 - 2.0f * a0;
        float d1 = t1 - 2.0f * a1;
        float d2 = t2 - 2.0f * a2;
        float d3 = t3 - 2.0f * a3;
        if (d0 < best) { best = d0; bi = c0 + 0; }
        if (d1 < best) { best = d1; bi = c0 + 1; }
        if (d2 < best) { best = d2; bi = c0 + 2; }
        if (d3 < best) { best = d3; bi = c0 + 3; }
    }

    __shared__ float sb[4][64];
    __shared__ int   si[4][64];
    sb[wid][lane] = best;
    si[wid][lane] = bi;
    __syncthreads();

    if (threadIdx.x < 64) {
        float b = sb[0][lane];
        int   i = si[0][lane];
#pragma unroll
        for (int w = 1; w < 4; ++w) {
            float ob = sb[w][lane];
            int   oi = si[w][lane];
            if (ob < b || (ob == b && oi < i)) { b = ob; i = oi; }
        }
        idx_out[token] = (float)i;
    }
}

// ---------------------------------------------------------------------------
// Kernel C: z_q_st + per-block f64 loss partials (unchanged).
// ---------------------------------------------------------------------------
__global__ __launch_bounds__(256) void output_kernel(const float* __restrict__ z,
                                                     const float* __restrict__ emb,
                                                     const float* __restrict__ idx_f,
                                                     float* __restrict__ zq_out,
                                                     double* __restrict__ partials) {
    int gid = blockIdx.x * 256 + threadIdx.x;
    int l = gid >> 6;
    int k = gid & 63;
    int idx = (int)idx_f[l];

    float zv = z[gid];
    float ev = emb[(idx << 6) + k];
    float t    = ev - zv;
    float outv = zv + t;
    zq_out[gid] = outv;

    float sq = t * t;

    __shared__ double red[256];
    red[threadIdx.x] = (double)sq;
    __syncthreads();
    for (int s = 128; s > 0; s >>= 1) {
        if (threadIdx.x < s) red[threadIdx.x] += red[threadIdx.x + s];
        __syncthreads();
    }
    if (threadIdx.x == 0) partials[blockIdx.x] = red[0];
}

// ---------------------------------------------------------------------------
// Kernel D: final deterministic reduction (unchanged).
// ---------------------------------------------------------------------------
__global__ __launch_bounds__(256) void loss_kernel(const double* __restrict__ partials,
                                                   float* __restrict__ loss_out) {
    __shared__ double red[256];
    int t = threadIdx.x;
    double s = 0.0;
    for (int i = 0; i < 64; ++i) s += partials[t * 64 + i];
    red[t] = s;
    __syncthreads();
    for (int st = 128; st > 0; st >>= 1) {
        if (t < st) red[t] += red[t + st];
        __syncthreads();
    }
    if (t == 0) {
        double m  = red[0] / (double)(L_TOK * DIM);
        float  mf = (float)m;
        loss_out[0] = 0.25f * mf + mf;
    }
}

extern "C" void kernel_launch(void* const* d_in, const int* in_sizes, int n_in,
                              void* d_out, int out_size, void* d_ws, size_t ws_size,
                              hipStream_t stream) {
    const float* z   = (const float*)d_in[0];
    const float* emb = (const float*)d_in[1];

    float* out   = (float*)d_out;
    float* zq    = out;                 // [0, 4194304)
    float* loss  = out + 4194304;       // [4194304]
    float* idxf  = out + 4194305;       // [4194305, 4259841)

    float*  esum     = (float*)d_ws;                          // 1024 f32
    double* partials = (double*)((char*)d_ws + 8192);         // 16384 f64

    esum_kernel  <<<4,     256, 0, stream>>>(emb, esum);
    argmin_kernel<<<1024,  256, 0, stream>>>(z, emb, esum, idxf);
    output_kernel<<<16384, 256, 0, stream>>>(z, emb, idxf, zq, partials);
    loss_kernel  <<<1,     256, 0, stream>>>(partials, loss);
}

// Round 7
// 180.132 us; speedup vs baseline: 4.4791x; 1.0214x over previous
//
#include <hip/hip_runtime.h>
#include <float.h>

#define L_TOK 65536
#define DIM   64
#define NCODE 1024

// ---------------------------------------------------------------------------
// Kernel A: per-code ||e||^2 (fp32), sequential-k chain.
// ---------------------------------------------------------------------------
__global__ __launch_bounds__(256) void esum_kernel(const float* __restrict__ emb,
                                                   float* __restrict__ esum) {
    int n = blockIdx.x * 256 + threadIdx.x;
    if (n >= NCODE) return;
    const float* e = emb + ((size_t)n << 6);
    float s = 0.f;
#pragma unroll
    for (int k = 0; k < DIM; ++k) s = fmaf(e[k], e[k], s);
    esum[n] = s;
}

// ---------------------------------------------------------------------------
// Kernel B: argmin.
// Evidence history:
//   r2/3/5/6: z "in registers" actually lives in AGPRs (VGPR_Count=44 with 64
//     live values is impossible otherwise) -> every use = v_accvgpr_read +
//     v_fmac = 2 VALU/FMA; VALU-issue 124us ~= 2x the 55-60us fmac floor.
//     Timing invariant across all pin attempts.
//   r4: z in LDS, but zt[k][lane] reads were LOOP-INVARIANT -> LICM hoisted
//     64 floats/thread -> scratch spill (2.4 GB HBM, 807us).
// This round: LDS z with
//   (a) opaque per-iteration SGPR zero folded into the LDS address -> reads
//       are loop-variant -> cannot be hoisted out of the code loop; pressure-
//       aware scheduling caps batching at the 64-VGPR budget (no spill);
//   (b) ds_read_b128 on row-major z[tok][k] with XOR-16B swizzle
//       (byte ^= (tok&7)<<4): 2 lanes/slot per 16-lane phase = conflict-free;
//   (c) 8 waves x 128 codes, launch_bounds(512,8) -> 100% occupancy.
// Numerics bitwise-identical to passing rounds: chunked float4 x,y,z,w reads
// in ascending chunks == sequential k=0..63 fmaf chains; d = fmaf(a,-2,
// zs+esum) == (zs+esum)-2a; ascending strict '<'; lowest-index tie-break.
// ---------------------------------------------------------------------------
__global__ __launch_bounds__(512, 8) void argmin_kernel(const float* __restrict__ z,
                                                        const float* __restrict__ emb,
                                                        const float* __restrict__ esum,
                                                        float* __restrict__ idx_out) {
    __shared__ float zl[64 * 64];   // swizzled row-major [tok][k], 16 KB
    __shared__ float sb[8][64];
    __shared__ int   si[8][64];

    const int t    = threadIdx.x;
    const int lane = t & 63;
    const int wid  = __builtin_amdgcn_readfirstlane(t >> 6);
    char* zbytes   = (char*)zl;

    // Stage z tile: coalesced global read, swizzled b128 LDS writes.
    {
        const int tok = t >> 3;          // 0..63
        const int kk  = (t & 7) * 8;     // 0,8,..,56
        const int swt = (tok & 7) << 4;
        const float* src = z + ((size_t)(blockIdx.x * 64 + tok) << 6) + kk;
        float4 v0 = ((const float4*)src)[0];
        float4 v1 = ((const float4*)src)[1];
        *(float4*)(zbytes + tok * 256 + ((kk * 4) ^ swt))      = v0;
        *(float4*)(zbytes + tok * 256 + ((kk * 4 + 16) ^ swt)) = v1;
    }
    __syncthreads();

    const int rowbase = lane * 256;
    const int sw      = (lane & 7) << 4;

    // ||z||^2, sequential k (chunk-ascending, x,y,z,w order).
    float zs = 0.f;
#pragma unroll
    for (int k0 = 0; k0 < 64; k0 += 4) {
        float4 zk = *(const float4*)(zbytes + rowbase + ((k0 * 4) ^ sw));
        zs = fmaf(zk.x, zk.x, zs);
        zs = fmaf(zk.y, zk.y, zs);
        zs = fmaf(zk.z, zk.z, zs);
        zs = fmaf(zk.w, zk.w, zs);
    }

    float best = FLT_MAX;
    int   bi   = 0;
    const int cbase = wid * 128;     // wave-uniform

    for (int c0 = cbase; c0 < cbase + 128; c0 += 8) {
        int zero = 0;
        asm volatile("" : "+s"(zero));   // opaque per-iter def: blocks LICM/PRE
        const int rb = rowbase + zero;   // of the LDS reads below

        const float* __restrict__ e0 = emb + ((size_t)(c0 + 0) << 6);
        const float* __restrict__ e1 = emb + ((size_t)(c0 + 1) << 6);
        const float* __restrict__ e2 = emb + ((size_t)(c0 + 2) << 6);
        const float* __restrict__ e3 = emb + ((size_t)(c0 + 3) << 6);
        const float* __restrict__ e4 = emb + ((size_t)(c0 + 4) << 6);
        const float* __restrict__ e5 = emb + ((size_t)(c0 + 5) << 6);
        const float* __restrict__ e6 = emb + ((size_t)(c0 + 6) << 6);
        const float* __restrict__ e7 = emb + ((size_t)(c0 + 7) << 6);
        float a0 = 0.f, a1 = 0.f, a2 = 0.f, a3 = 0.f;
        float a4 = 0.f, a5 = 0.f, a6 = 0.f, a7 = 0.f;
#pragma unroll
        for (int k0 = 0; k0 < 64; k0 += 4) {
            float4 zk = *(const float4*)(zbytes + rb + ((k0 * 4) ^ sw));
            a0 = fmaf(zk.x, e0[k0+0], a0); a0 = fmaf(zk.y, e0[k0+1], a0);
            a0 = fmaf(zk.z, e0[k0+2], a0); a0 = fmaf(zk.w, e0[k0+3], a0);
            a1 = fmaf(zk.x, e1[k0+0], a1); a1 = fmaf(zk.y, e1[k0+1], a1);
            a1 = fmaf(zk.z, e1[k0+2], a1); a1 = fmaf(zk.w, e1[k0+3], a1);
            a2 = fmaf(zk.x, e2[k0+0], a2); a2 = fmaf(zk.y, e2[k0+1], a2);
            a2 = fmaf(zk.z, e2[k0+2], a2); a2 = fmaf(zk.w, e2[k0+3], a2);
            a3 = fmaf(zk.x, e3[k0+0], a3); a3 = fmaf(zk.y, e3[k0+1], a3);
            a3 = fmaf(zk.z, e3[k0+2], a3); a3 = fmaf(zk.w, e3[k0+3], a3);
            a4 = fmaf(zk.x, e4[k0+0], a4); a4 = fmaf(zk.y, e4[k0+1], a4);
            a4 = fmaf(zk.z, e4[k0+2], a4); a4 = fmaf(zk.w, e4[k0+3], a4);
            a5 = fmaf(zk.x, e5[k0+0], a5); a5 = fmaf(zk.y, e5[k0+1], a5);
            a5 = fmaf(zk.z, e5[k0+2], a5); a5 = fmaf(zk.w, e5[k0+3], a5);
            a6 = fmaf(zk.x, e6[k0+0], a6); a6 = fmaf(zk.y, e6[k0+1], a6);
            a6 = fmaf(zk.z, e6[k0+2], a6); a6 = fmaf(zk.w, e6[k0+3], a6);
            a7 = fmaf(zk.x, e7[k0+0], a7); a7 = fmaf(zk.y, e7[k0+1], a7);
            a7 = fmaf(zk.z, e7[k0+2], a7); a7 = fmaf(zk.w, e7[k0+3], a7);
        }
        float d0 = fmaf(a0, -2.0f, zs + esum[c0 + 0]);
        float d1 = fmaf(a1, -2.0f, zs + esum[c0 + 1]);
        float d2 = fmaf(a2, -2.0f, zs + esum[c0 + 2]);
        float d3 = fmaf(a3, -2.0f, zs + esum[c0 + 3]);
        float d4 = fmaf(a4, -2.0f, zs + esum[c0 + 4]);
        float d5 = fmaf(a5, -2.0f, zs + esum[c0 + 5]);
        float d6 = fmaf(a6, -2.0f, zs + esum[c0 + 6]);
        float d7 = fmaf(a7, -2.0f, zs + esum[c0 + 7]);
        if (d0 < best) { best = d0; bi = c0 + 0; }
        if (d1 < best) { best = d1; bi = c0 + 1; }
        if (d2 < best) { best = d2; bi = c0 + 2; }
        if (d3 < best) { best = d3; bi = c0 + 3; }
        if (d4 < best) { best = d4; bi = c0 + 4; }
        if (d5 < best) { best = d5; bi = c0 + 5; }
        if (d6 < best) { best = d6; bi = c0 + 6; }
        if (d7 < best) { best = d7; bi = c0 + 7; }
    }

    sb[wid][lane] = best;
    si[wid][lane] = bi;
    __syncthreads();

    if (t < 64) {
        float b = sb[0][lane];
        int   i = si[0][lane];
#pragma unroll
        for (int w = 1; w < 8; ++w) {
            float ob = sb[w][lane];
            int   oi = si[w][lane];
            if (ob < b || (ob == b && oi < i)) { b = ob; i = oi; }
        }
        idx_out[blockIdx.x * 64 + lane] = (float)i;
    }
}

// ---------------------------------------------------------------------------
// Kernel C: z_q_st + per-block f64 loss partials (unchanged).
// ---------------------------------------------------------------------------
__global__ __launch_bounds__(256) void output_kernel(const float* __restrict__ z,
                                                     const float* __restrict__ emb,
                                                     const float* __restrict__ idx_f,
                                                     float* __restrict__ zq_out,
                                                     double* __restrict__ partials) {
    int gid = blockIdx.x * 256 + threadIdx.x;
    int l = gid >> 6;
    int k = gid & 63;
    int idx = (int)idx_f[l];

    float zv = z[gid];
    float ev = emb[(idx << 6) + k];
    float t    = ev - zv;
    float outv = zv + t;
    zq_out[gid] = outv;

    float sq = t * t;

    __shared__ double red[256];
    red[threadIdx.x] = (double)sq;
    __syncthreads();
    for (int s = 128; s > 0; s >>= 1) {
        if (threadIdx.x < s) red[threadIdx.x] += red[threadIdx.x + s];
        __syncthreads();
    }
    if (threadIdx.x == 0) partials[blockIdx.x] = red[0];
}

// ---------------------------------------------------------------------------
// Kernel D: final deterministic reduction (unchanged).
// ---------------------------------------------------------------------------
__global__ __launch_bounds__(256) void loss_kernel(const double* __restrict__ partials,
                                                   float* __restrict__ loss_out) {
    __shared__ double red[256];
    int t = threadIdx.x;
    double s = 0.0;
    for (int i = 0; i < 64; ++i) s += partials[t * 64 + i];
    red[t] = s;
    __syncthreads();
    for (int st = 128; st > 0; st >>= 1) {
        if (t < st) red[t] += red[t + st];
        __syncthreads();
    }
    if (t == 0) {
        double m  = red[0] / (double)(L_TOK * DIM);
        float  mf = (float)m;
        loss_out[0] = 0.25f * mf + mf;
    }
}

extern "C" void kernel_launch(void* const* d_in, const int* in_sizes, int n_in,
                              void* d_out, int out_size, void* d_ws, size_t ws_size,
                              hipStream_t stream) {
    const float* z   = (const float*)d_in[0];
    const float* emb = (const float*)d_in[1];

    float* out   = (float*)d_out;
    float* zq    = out;                 // [0, 4194304)
    float* loss  = out + 4194304;       // [4194304]
    float* idxf  = out + 4194305;       // [4194305, 4259841)

    float*  esum     = (float*)d_ws;                          // 1024 f32
    double* partials = (double*)((char*)d_ws + 8192);         // 16384 f64

    esum_kernel  <<<4,     256, 0, stream>>>(emb, esum);
    argmin_kernel<<<1024,  512, 0, stream>>>(z, emb, esum, idxf);
    output_kernel<<<16384, 256, 0, stream>>>(z, emb, idxf, zq, partials);
    loss_kernel  <<<1,     256, 0, stream>>>(partials, loss);
}